// Round 3
// baseline (181.753 us; speedup 1.0000x reference)
//
#include <hip/hip_runtime.h>
#include <math.h>

typedef __bf16 bf16;
typedef __attribute__((ext_vector_type(4))) __bf16 bf16x4;
typedef __attribute__((ext_vector_type(8))) __bf16 bf16x8;
typedef __attribute__((ext_vector_type(4))) float f32x4;

#define B_SZ 2
#define T_SZ 1024
#define DM_SZ 1024
#define H_SZ 16
#define D_SZ 64
#define L_SZ 12
#define M_ROWS 2048      // B*T
#define N_PAD 3328       // q(1024)+k(1024)+v(1024)+logit(192)+pad(64)

__device__ __forceinline__ f32x4 mfma_16x16x32(bf16x8 a, bf16x8 b, f32x4 c) {
  return __builtin_amdgcn_mfma_f32_16x16x32_bf16(a, b, c, 0, 0, 0);
}

// async global->LDS, 16B/lane; LDS dest = wave-uniform base + lane*16.
__device__ __forceinline__ void gload_lds16(const bf16* g, bf16* l) {
  __builtin_amdgcn_global_load_lds((const __attribute__((address_space(1))) void*)g,
                                   (__attribute__((address_space(3))) void*)l,
                                   16, 0, 0);
}

// ---------------------------------------------------------------------------
// Prep: z=0..3 weight transposes (1024x1024), z=4 lw transpose (1024x192),
// z=5 x fp32->bf16 cast. Grid (16,16,6), block 256.
// ---------------------------------------------------------------------------
__global__ __launch_bounds__(256) void k_prep(
    const float* __restrict__ x, bf16* __restrict__ xb,
    const float* __restrict__ qw, const float* __restrict__ kw,
    const float* __restrict__ vw, const float* __restrict__ ow,
    const float* __restrict__ lw,
    bf16* __restrict__ wqkvT, bf16* __restrict__ owT) {
  const int z = blockIdx.z;
  const int t = threadIdx.x;
  if (z == 5) {  // cast 2048x1024 fp32 -> bf16, 8192 els per block
    const size_t base = ((size_t)blockIdx.y * 16 + blockIdx.x) * 8192 + t * 32;
#pragma unroll
    for (int u = 0; u < 4; ++u) {
      const float* p = x + base + u * 8;
      f32x4 a = *(const f32x4*)p;
      f32x4 b = *(const f32x4*)(p + 4);
      bf16x8 o;
#pragma unroll
      for (int e = 0; e < 4; ++e) { o[e] = (bf16)a[e]; o[e + 4] = (bf16)b[e]; }
      *(bf16x8*)(xb + base + u * 8) = o;
    }
    return;
  }
  __shared__ __align__(16) bf16 tile[64][66];
  const float* in; bf16* out; int C = 1024;
  if (z == 0)      { in = qw; out = wqkvT; }
  else if (z == 1) { in = kw; out = wqkvT + (size_t)1024 * DM_SZ; }
  else if (z == 2) { in = vw; out = wqkvT + (size_t)2048 * DM_SZ; }
  else if (z == 3) { in = ow; out = owT; }
  else             { in = lw; out = wqkvT + (size_t)3072 * DM_SZ; C = 192;
                     if (blockIdx.x >= 3) return; }
  const int tc = blockIdx.x * 64;
  const int tr = blockIdx.y * 64;
  const int r = t >> 2;
  const int c4 = (t & 3) << 4;
  const float* src = in + (size_t)(tr + r) * C + tc + c4;
  f32x4 f0 = *(const f32x4*)(src);
  f32x4 f1 = *(const f32x4*)(src + 4);
  f32x4 f2 = *(const f32x4*)(src + 8);
  f32x4 f3 = *(const f32x4*)(src + 12);
#pragma unroll
  for (int e = 0; e < 4; ++e) {
    tile[r][c4 + e]      = (bf16)f0[e];
    tile[r][c4 + 4 + e]  = (bf16)f1[e];
    tile[r][c4 + 8 + e]  = (bf16)f2[e];
    tile[r][c4 + 12 + e] = (bf16)f3[e];
  }
  __syncthreads();
  bf16x8 w0, w1;
#pragma unroll
  for (int e = 0; e < 8; ++e) { w0[e] = tile[c4 + e][r]; w1[e] = tile[c4 + 8 + e][r]; }
  bf16* dst = out + (size_t)(tc + r) * DM_SZ + tr + c4;
  *(bf16x8*)(dst) = w0;
  *(bf16x8*)(dst + 8) = w1;
}

// ---------------------------------------------------------------------------
// Fused QKVL GEMM: xb(2048x1024) x wqkvT(3328x1024) -> Qp/Kp (phi, bf16),
// VTg (plain, transposed in epilogue), logit (f32, raw). Tile 128x128, BK=64.
// 512 threads / 8 waves (4M x 2N, wave-tile 32x64): same grid & staging as
// the 4-wave version but 2x resident waves (13/CU vs 6.4) for latency
// hiding at this modest grid size. Double-buffered, 1 barrier per K-step.
// ---------------------------------------------------------------------------
__global__ __launch_bounds__(512) void k_gemm_qkvl(
    const bf16* __restrict__ A, const bf16* __restrict__ Wt,
    const float* __restrict__ qb, const float* __restrict__ kb,
    const float* __restrict__ vb, const float* __restrict__ lb,
    bf16* __restrict__ Qp, bf16* __restrict__ Kp,
    bf16* __restrict__ VTg, float* __restrict__ logit) {
  __shared__ __align__(16) char smem[65536];  // As2|Bs2 (64KB) / Trt (34KB)
  bf16* Asb = (bf16*)smem;           // [2][8192]
  bf16* Bsb = Asb + 16384;           // [2][8192]
  const int nb = blockIdx.x * 128;
  const int mb = blockIdx.y * 128;
  const int t = threadIdx.x;
  const int wv = t >> 6;             // 0..7
  const int lane = t & 63;
  const int l16 = lane & 15;
  const int quad = lane >> 4;
  const int wm = (wv & 3) * 32;      // 4 wave-rows
  const int wn = (wv >> 2) * 64;     // 2 wave-cols

  const int trow = t >> 3;           // 0..63
  const int tcol = (t & 7) * 8;

  const f32x4 zero4 = {0.f, 0.f, 0.f, 0.f};
  f32x4 acc[2][4];
#pragma unroll
  for (int i = 0; i < 2; ++i)
#pragma unroll
    for (int j = 0; j < 4; ++j) acc[i][j] = zero4;

  const bf16* ag = A + (size_t)(mb + trow) * DM_SZ + tcol;
  const bf16* bg = Wt + (size_t)(nb + trow) * DM_SZ + tcol;

  auto stage = [&](int k0, int buf) {
    bf16* As = Asb + buf * 8192;
    bf16* Bs = Bsb + buf * 8192;
    gload_lds16(ag + k0, As + t * 8);
    gload_lds16(ag + (size_t)64 * DM_SZ + k0, As + 4096 + t * 8);
    gload_lds16(bg + k0, Bs + t * 8);
    gload_lds16(bg + (size_t)64 * DM_SZ + k0, Bs + 4096 + t * 8);
  };

  stage(0, 0);
  for (int k0 = 0; k0 < DM_SZ; k0 += 64) {
    const int cur = (k0 >> 6) & 1;
    __syncthreads();  // drains vmcnt for buf[cur]; frees buf[cur^1]
    if (k0 + 64 < DM_SZ) stage(k0 + 64, cur ^ 1);
    const bf16* As = Asb + cur * 8192;
    const bf16* Bs = Bsb + cur * 8192;
#pragma unroll
    for (int ks = 0; ks < 2; ++ks) {
      bf16x8 af[2];
#pragma unroll
      for (int mi = 0; mi < 2; ++mi)
        af[mi] = *(const bf16x8*)(As + (wm + mi * 16 + l16) * 64 + ks * 32 + quad * 8);
#pragma unroll
      for (int ni = 0; ni < 4; ++ni) {
        bf16x8 bfr = *(const bf16x8*)(Bs + (wn + ni * 16 + l16) * 64 + ks * 32 + quad * 8);
#pragma unroll
        for (int mi = 0; mi < 2; ++mi)
          acc[mi][ni] = mfma_16x16x32(af[mi], bfr, acc[mi][ni]);
      }
    }
  }

  const int seg = nb >> 10;  // 0=q 1=k 2=v 3=logit
  if (seg < 2) {
    const float* bias = seg == 0 ? qb : kb;
    bf16* outp = seg == 0 ? Qp : Kp;
    const int c0 = (nb & 1023) + wn;
#pragma unroll
    for (int ni = 0; ni < 4; ++ni) {
      const int col = c0 + ni * 16 + l16;
      const float bv = bias[col];
#pragma unroll
      for (int mi = 0; mi < 2; ++mi) {
#pragma unroll
        for (int r = 0; r < 4; ++r) {
          const int row = mb + wm + mi * 16 + quad * 4 + r;
          float v = acc[mi][ni][r] + bv;
          v = (v > 0.f) ? (v + 1.f) : __expf(v);
          outp[(size_t)row * DM_SZ + col] = (bf16)v;
        }
      }
    }
  } else if (seg == 2) {
    // V: bias, transpose via LDS (stride 136), store VTg[b*1024+d][t]
    bf16* Trt = (bf16*)smem;
    const int cb = nb - 2048;
    __syncthreads();  // K-loop LDS frag reads complete before overwrite
#pragma unroll
    for (int ni = 0; ni < 4; ++ni) {
      const int nloc = wn + ni * 16 + l16;
      const float bv = vb[cb + nloc];
#pragma unroll
      for (int mi = 0; mi < 2; ++mi) {
        const int mloc = wm + mi * 16 + quad * 4;
        bf16x4 pk;
#pragma unroll
        for (int r = 0; r < 4; ++r) pk[r] = (bf16)(acc[mi][ni][r] + bv);
        *(bf16x4*)&Trt[nloc * 136 + mloc] = pk;
      }
    }
    __syncthreads();
    const int dn = t >> 2, ch = t & 3;   // 128 d-rows, 4 col-chunks of 32
    const int bq = mb >> 10;
    const int m0g = mb & 1023;
    bf16* dst = VTg + ((size_t)(bq * 1024 + cb + dn)) * T_SZ + m0g + ch * 32;
    const bf16* srcl = Trt + dn * 136 + ch * 32;
#pragma unroll
    for (int e = 0; e < 4; ++e)
      *(bf16x8*)(dst + e * 8) = *(const bf16x8*)(srcl + e * 8);
  } else {
    const int lc0 = (nb - 3072) + wn;
#pragma unroll
    for (int ni = 0; ni < 4; ++ni) {
      const int lcol = lc0 + ni * 16 + l16;
      if (lcol < H_SZ * L_SZ) {
        const float bv = lb[lcol];
#pragma unroll
        for (int mi = 0; mi < 2; ++mi) {
#pragma unroll
          for (int r = 0; r < 4; ++r) {
            const int row = mb + wm + mi * 16 + quad * 4 + r;
            logit[(size_t)row * (H_SZ * L_SZ) + lcol] = acc[mi][ni][r] + bv;
          }
        }
      }
    }
  }
}

// ---------------------------------------------------------------------------
// Leaf build: per (bh, jt) compute G[d2][d1] = sum_j V[j][d2]*Kp[j][d1]
// (64x64, f32) and ksum[d1] = sum_j Kp[j][d1]. Grid 512, block 256.
// ---------------------------------------------------------------------------
__global__ __launch_bounds__(256) void k_build(const bf16* __restrict__ Kp,
                                               const bf16* __restrict__ VTg,
                                               float* __restrict__ Hbuf,
                                               float* __restrict__ ksumbuf) {
  __shared__ __align__(16) bf16 KTs[64][72];  // [d1][j]
  __shared__ __align__(16) bf16 VTs[64][72];  // [d2][j]
  const int idx = blockIdx.x;
  const int bh = idx & 31;
  const int jt = idx >> 5;
  const int b = bh >> 4, h = bh & 15;
  const int t = threadIdx.x;
  const int wv = t >> 6, lane = t & 63, l16 = lane & 15, quad = lane >> 4;
  const int r = t >> 2, c = (t & 3) << 4;

  // stage V^T rows directly (VTg is [d][t])
  const bf16* vp = VTg + ((size_t)bh * 64 + r) * T_SZ + jt * 64 + c;
  bf16x8 v0 = *(const bf16x8*)vp;
  bf16x8 v1 = *(const bf16x8*)(vp + 8);
  // Kp rows [j][d] -> transpose into KTs[d][j]
  const bf16* kp = Kp + ((size_t)b * T_SZ + jt * 64 + r) * DM_SZ + h * 64 + c;
  bf16x8 k0 = *(const bf16x8*)kp;
  bf16x8 k1 = *(const bf16x8*)(kp + 8);
  *(bf16x8*)&VTs[r][c] = v0;
  *(bf16x8*)&VTs[r][c + 8] = v1;
#pragma unroll
  for (int e = 0; e < 8; ++e) { KTs[c + e][r] = k0[e]; KTs[c + 8 + e][r] = k1[e]; }
  __syncthreads();

  if (t < 64) {
    float s = 0.f;
#pragma unroll
    for (int j = 0; j < 64; ++j) s += (float)KTs[t][j];
    ksumbuf[((size_t)bh * 16 + jt) * 64 + t] = s;
  }

  const f32x4 zero4 = {0.f, 0.f, 0.f, 0.f};
  f32x4 acc[4];
#pragma unroll
  for (int tn = 0; tn < 4; ++tn) acc[tn] = zero4;
#pragma unroll
  for (int ks = 0; ks < 2; ++ks) {
    bf16x8 af = *(const bf16x8*)&VTs[wv * 16 + l16][ks * 32 + quad * 8];
#pragma unroll
    for (int tn = 0; tn < 4; ++tn) {
      bf16x8 bfr = *(const bf16x8*)&KTs[tn * 16 + l16][ks * 32 + quad * 8];
      acc[tn] = mfma_16x16x32(af, bfr, acc[tn]);
    }
  }
  float* hp = Hbuf + ((size_t)bh * 16 + jt) * 4096;
#pragma unroll
  for (int tn = 0; tn < 4; ++tn)
#pragma unroll
    for (int rr = 0; rr < 4; ++rr)
      hp[(wv * 16 + quad * 4 + rr) * 64 + tn * 16 + l16] = acc[tn][rr];
}

// ---------------------------------------------------------------------------
// Fenwick-associated attention. Per query tile it:
//   off-diag: [0,it) decomposes into <=4 aligned Fenwick blocks (level 6+g,
//   g=ctz on the walk). Group-sum leaf G matrices (f32) -> Ms[g] (bf16),
//   y_g = Q*Ms[g] via MFMA, num_i += w_{i,6+g}*y_g[i]. den via dv-MFMA with
//   the 4 group ksum vectors packed as B rows 0..3.
//   Row 63 uses levels fls((it+1)^jt): exact weighted leaf-stream (f32 regs)
//   -> y63/dsum63 correction, standard contributions masked for that row.
//   Diagonal tile: exact per-element level + causal mask (as before).
// Grid 512, block 256.
// ---------------------------------------------------------------------------
__global__ __launch_bounds__(256) void k_attn(const bf16* __restrict__ Qp,
                                              const bf16* __restrict__ Kp,
                                              const bf16* __restrict__ VTg,
                                              const float* __restrict__ Lg,
                                              const float* __restrict__ Hbuf,
                                              const float* __restrict__ ksumbuf,
                                              bf16* __restrict__ O) {
  __shared__ __align__(16) bf16 Ks[64][72];
  __shared__ __align__(16) bf16 VTs[64][72];
  __shared__ __align__(16) bf16 Ms[4][64][72];
  __shared__ __align__(16) bf16 Pl[4][16][80];
  __shared__ __align__(16) bf16 Bdvs[16][72];
  __shared__ float Ws[64 * L_SZ];
  __shared__ float q63s[64];
  __shared__ float y63s[64];
  __shared__ float dsum63s;

  const int idx = blockIdx.x;
  const int s = idx >> 5;
  const int bh = idx & 31;
  const int it = (s < 8) ? (15 - s) : (s - 8);  // heavy-first balance
  const int b = bh >> 4;
  const int h = bh & 15;
  const int i0 = it * 64;
  const int t = threadIdx.x;
  const int wv = t >> 6;
  const int lane = t & 63;
  const int l16 = lane & 15;
  const int quad = lane >> 4;
  const int m0 = wv * 16;
  const size_t base_bt = (size_t)b * T_SZ;

  // init
  for (int i = t; i < 16 * 72; i += 256) ((short*)Bdvs)[i] = 0;
  if (t < 64) y63s[t] = 0.f;
  if (t == 0) dsum63s = 0.f;

  // Q fragments (A operand, k = d)
  const bf16* qptr = Qp + (base_bt + i0 + m0 + l16) * DM_SZ + h * 64 + quad * 8;
  const bf16x8 aq0 = *(const bf16x8*)(qptr);
  const bf16x8 aq1 = *(const bf16x8*)(qptr + 32);

  // q63 staging
  if (t < 64) q63s[t] = (float)Qp[(base_bt + i0 + 63) * DM_SZ + h * 64 + t];

  // diag K/V tile loads to regs (written to LDS after sync1)
  const int sr = t >> 2;
  const int sc = (t & 3) << 4;
  const bf16* kpg = Kp + (base_bt + i0 + sr) * DM_SZ + h * 64 + sc;
  const bf16x8 kv0 = *(const bf16x8*)(kpg);
  const bf16x8 kv1 = *(const bf16x8*)(kpg + 8);
  const bf16* vpg = VTg + ((size_t)bh * 64 + sr) * T_SZ + i0 + sc;
  const bf16x8 vv0 = *(const bf16x8*)(vpg);
  const bf16x8 vv1 = *(const bf16x8*)(vpg + 8);

  if (t < 64) {  // fused softmax for this block's 64 query rows
    const float* lp = Lg + (base_bt + i0 + t) * (H_SZ * L_SZ) + h * L_SZ;
    float v[L_SZ];
    float m = -1e30f;
#pragma unroll
    for (int l = 0; l < L_SZ; ++l) { v[l] = lp[l]; m = fmaxf(m, v[l]); }
    float sum = 0.f;
#pragma unroll
    for (int l = 0; l < L_SZ; ++l) { v[l] = __expf(v[l] - m); sum += v[l]; }
    const float inv = 1.f / sum;
#pragma unroll
    for (int l = 0; l < L_SZ; ++l) Ws[t * L_SZ + l] = v[l] * inv;
  }

  __syncthreads();  // Ws, q63s, zero-inits visible

  // write diag tiles (padded 72: read stride 144B -> 2-way = free)
  *(bf16x8*)&Ks[sr][sc] = kv0;
  *(bf16x8*)&Ks[sr][sc + 8] = kv1;
  *(bf16x8*)&VTs[sr][sc] = vv0;
  *(bf16x8*)&VTs[sr][sc + 8] = vv1;

  const int il_base = m0 + quad * 4;
  const f32x4 zero4 = {0.f, 0.f, 0.f, 0.f};
  f32x4 accn[4];
#pragma unroll
  for (int tn = 0; tn < 4; ++tn) accn[tn] = zero4;
  float den[4] = {0.f, 0.f, 0.f, 0.f};

  // ---- phase 2: group-sum leaves + row-63 weighted stream ----
  if (it > 0) {
    const float* hb = Hbuf + (size_t)bh * 16 * 4096;
    const float* ksb = ksumbuf + (size_t)bh * 16 * 64;
    f32x4 m63a[4];
#pragma unroll
    for (int i = 0; i < 4; ++i) m63a[i] = zero4;
    float dv63 = 0.f;
    int x = it;
    while (x > 0) {
      const int g = __builtin_ctz((unsigned)x);
      const int lo = x - (1 << g);
      f32x4 ma[4];
#pragma unroll
      for (int i = 0; i < 4; ++i) ma[i] = zero4;
      float dva = 0.f;
      for (int jt = lo; jt < x; ++jt) {
        const float wB = Ws[63 * L_SZ + 6 + (31 - __clz((unsigned)((it + 1) ^ jt)))];
        const float* lp = hb + jt * 4096 + t * 16;
#pragma unroll
        for (int i = 0; i < 4; ++i) {
          f32x4 hv = *(const f32x4*)(lp + i * 4);
#pragma unroll
          for (int e = 0; e < 4; ++e) {
            ma[i][e] += hv[e];
            m63a[i][e] += wB * hv[e];
          }
        }
        if (t < 64) {
          const float ksv = ksb[jt * 64 + t];
          dva += ksv;
          dv63 += wB * ksv;
        }
      }
      // flush group g: Ms[g][d2][d1], el e = t*16+i*4+e2: d2=t>>2, d1=(t&3)*16+...
      bf16x8 o0, o1;
#pragma unroll
      for (int e = 0; e < 4; ++e) {
        o0[e] = (bf16)ma[0][e]; o0[e + 4] = (bf16)ma[1][e];
        o1[e] = (bf16)ma[2][e]; o1[e + 4] = (bf16)ma[3][e];
      }
      *(bf16x8*)&Ms[g][t >> 2][(t & 3) << 4] = o0;
      *(bf16x8*)&Ms[g][t >> 2][((t & 3) << 4) + 8] = o1;
      if (t < 64) Bdvs[g][t] = (bf16)dva;
      x = lo;
    }
    // y63[d2] = sum_d1 q63[d1] * Mw63[d2][d1]; thread owns row d2=t>>2,
    // cols d1 = (t&3)*16 .. +16
    float p63 = 0.f;
    const int d1b = (t & 3) << 4;
#pragma unroll
    for (int i = 0; i < 4; ++i)
#pragma unroll
      for (int e = 0; e < 4; ++e) p63 += q63s[d1b + i * 4 + e] * m63a[i][e];
    p63 += __shfl_xor(p63, 1, 64);
    p63 += __shfl_xor(p63, 2, 64);
    if ((t & 3) == 0) y63s[t >> 2] = p63;
    if (t < 64) {
      float pd = q63s[t] * dv63;
      pd += __shfl_xor(pd, 1, 64);
      pd += __shfl_xor(pd, 2, 64);
      pd += __shfl_xor(pd, 4, 64);
      pd += __shfl_xor(pd, 8, 64);
      pd += __shfl_xor(pd, 16, 64);
      pd += __shfl_xor(pd, 32, 64);
      if (t == 0) dsum63s = pd;
    }
  }
  __syncthreads();  // Ms, Bdvs, Ks, VTs, y63s, dsum63s visible

  // ---- phase 3: group GEMMs + dv MFMA ----
  if (it > 0) {
    int x = it;
    while (x > 0) {
      const int g = __builtin_ctz((unsigned)x);
      f32x4 ya[4];
#pragma unroll
      for (int tn = 0; tn < 4; ++tn) ya[tn] = zero4;
#pragma unroll
      for (int ks = 0; ks < 2; ++ks) {
        const bf16x8 af = ks ? aq1 : aq0;
#pragma unroll
        for (int tn = 0; tn < 4; ++tn) {
          bf16x8 bfr = *(const bf16x8*)&Ms[g][tn * 16 + l16][ks * 32 + quad * 8];
          ya[tn] = mfma_16x16x32(af, bfr, ya[tn]);
        }
      }
      float wg[4];
#pragma unroll
      for (int r = 0; r < 4; ++r) {
        const int il = il_base + r;
        wg[r] = (il == 63) ? 0.f : Ws[il * L_SZ + 6 + g];
      }
#pragma unroll
      for (int tn = 0; tn < 4; ++tn)
#pragma unroll
        for (int r = 0; r < 4; ++r) accn[tn][r] += wg[r] * ya[tn][r];
      x -= 1 << g;
    }
    f32x4 da = zero4;
#pragma unroll
    for (int ks = 0; ks < 2; ++ks) {
      const bf16x8 af = ks ? aq1 : aq0;
      bf16x8 bfr = *(const bf16x8*)&Bdvs[l16][ks * 32 + quad * 8];
      da = mfma_16x16x32(af, bfr, da);
    }
#pragma unroll
    for (int r = 0; r < 4; ++r) {
      const int il = il_base + r;
      const float wd = (il == 63) ? 0.f : Ws[il * L_SZ + 6 + (l16 & 3)];
      den[r] += wd * da[r];
    }
  }

  // ---- phase 4: diagonal tile (exact levels + causal mask) ----
  {
    f32x4 sacc[4];
    __builtin_amdgcn_s_setprio(1);
#pragma unroll
    for (int tn = 0; tn < 4; ++tn) {
      sacc[tn] = zero4;
      bf16x8 bk0 = *(const bf16x8*)&Ks[tn * 16 + l16][quad * 8];
      bf16x8 bk1 = *(const bf16x8*)&Ks[tn * 16 + l16][32 + quad * 8];
      sacc[tn] = mfma_16x16x32(aq0, bk0, sacc[tn]);
      sacc[tn] = mfma_16x16x32(aq1, bk1, sacc[tn]);
    }
    __builtin_amdgcn_s_setprio(0);
#pragma unroll
    for (int tn = 0; tn < 4; ++tn) {
#pragma unroll
      for (int r = 0; r < 4; ++r) {
        const int il = il_base + r;
        const int ig = i0 + il;
        const int jg = i0 + tn * 16 + l16;
        float p = 0.f;
        if (jg <= ig) {
          const int lvl = 31 - __clz((unsigned)((ig + 1) ^ jg));
          p = sacc[tn][r] * Ws[il * L_SZ + lvl];
        }
        den[r] += p;
        Pl[wv][quad * 4 + r][(tn * 16 + l16) ^ (quad << 4)] = (bf16)p;
      }
    }
    __builtin_amdgcn_s_setprio(1);
#pragma unroll
    for (int ks = 0; ks < 2; ++ks) {
      bf16x8 apf = *(const bf16x8*)&Pl[wv][l16][(ks * 32 + quad * 8) ^ ((l16 >> 2) << 4)];
#pragma unroll
      for (int tn = 0; tn < 4; ++tn) {
        bf16x8 bvf = *(const bf16x8*)&VTs[tn * 16 + l16][ks * 32 + quad * 8];
        accn[tn] = mfma_16x16x32(apf, bvf, accn[tn]);
      }
    }
    __builtin_amdgcn_s_setprio(0);
  }

  // ---- reduce + output ----
#pragma unroll
  for (int r = 0; r < 4; ++r) {
    float d = den[r];
    d += __shfl_xor(d, 1, 64);
    d += __shfl_xor(d, 2, 64);
    d += __shfl_xor(d, 4, 64);
    d += __shfl_xor(d, 8, 64);
    den[r] = d;
  }
  if (il_base + 3 == 63) den[3] += dsum63s;  // row-63 off-diag denominator
#pragma unroll
  for (int r = 0; r < 4; ++r) den[r] = fmaxf(den[r], 1e-6f);

#pragma unroll
  for (int tn = 0; tn < 4; ++tn) {
#pragma unroll
    for (int r = 0; r < 4; ++r) {
      const int il = il_base + r;
      float v = accn[tn][r];
      if (il == 63) v += y63s[tn * 16 + l16];
      O[(base_bt + i0 + il) * DM_SZ + h * 64 + tn * 16 + l16] =
          (bf16)(v / den[r]);
    }
  }
}

// ---------------------------------------------------------------------------
// Output GEMM: attn(2048x1024) x owT(1024x1024) + ob -> f32 out.
// Tile 64x64, grid (16,32)=512 blocks, double-buffered global_load_lds with
// one barrier per K-step (prefetch-ahead, latency hidden under MFMA).
// ---------------------------------------------------------------------------
__global__ __launch_bounds__(256) void k_gemm_out(const bf16* __restrict__ A,
                                                  const bf16* __restrict__ Wt,
                                                  const float* __restrict__ ob,
                                                  float* __restrict__ out) {
  __shared__ __align__(16) bf16 As[2][64 * 64];
  __shared__ __align__(16) bf16 Bs[2][64 * 64];
  const int nb = blockIdx.x * 64;
  const int mb = blockIdx.y * 64;
  const int t = threadIdx.x;
  const int wv = t >> 6;
  const int lane = t & 63;
  const int l16 = lane & 15;
  const int quad = lane >> 4;
  const int wm = wv * 16;

  const int trow = t >> 3;
  const int tcol = (t & 7) * 8;

  const f32x4 zero4 = {0.f, 0.f, 0.f, 0.f};
  f32x4 acc[4];
#pragma unroll
  for (int j = 0; j < 4; ++j) acc[j] = zero4;

  const bf16* ag = A + (size_t)(mb + trow) * DM_SZ + tcol;
  const bf16* bg = Wt + (size_t)(nb + trow) * DM_SZ + tcol;

  auto stageg = [&](int k0, int buf) {
    gload_lds16(ag + k0, As[buf] + t * 8);
    gload_lds16(ag + (size_t)32 * DM_SZ + k0, As[buf] + 2048 + t * 8);
    gload_lds16(bg + k0, Bs[buf] + t * 8);
    gload_lds16(bg + (size_t)32 * DM_SZ + k0, Bs[buf] + 2048 + t * 8);
  };

  stageg(0, 0);
  for (int k0 = 0; k0 < DM_SZ; k0 += 64) {
    const int cur = (k0 >> 6) & 1;
    __syncthreads();  // drains vmcnt for buf[cur]; frees buf[cur^1]
    if (k0 + 64 < DM_SZ) stageg(k0 + 64, cur ^ 1);
#pragma unroll
    for (int ks = 0; ks < 2; ++ks) {
      bf16x8 af = *(const bf16x8*)(As[cur] + (wm + l16) * 64 + ks * 32 + quad * 8);
#pragma unroll
      for (int ni = 0; ni < 4; ++ni) {
        bf16x8 bfr = *(const bf16x8*)(Bs[cur] + (ni * 16 + l16) * 64 + ks * 32 + quad * 8);
        acc[ni] = mfma_16x16x32(af, bfr, acc[ni]);
      }
    }
  }
#pragma unroll
  for (int ni = 0; ni < 4; ++ni) {
    const int col = nb + ni * 16 + l16;
    const float bv = ob[col];
#pragma unroll
    for (int r = 0; r < 4; ++r) {
      const int row = mb + wm + quad * 4 + r;
      out[(size_t)row * DM_SZ + col] = acc[ni][r] + bv;
    }
  }
}

// ---------------------------------------------------------------------------
extern "C" void kernel_launch(void* const* d_in, const int* in_sizes, int n_in,
                              void* d_out, int out_size, void* d_ws, size_t ws_size,
                              hipStream_t stream) {
  (void)in_sizes; (void)n_in; (void)out_size; (void)ws_size;
  const float* x  = (const float*)d_in[0];
  const float* qw = (const float*)d_in[1];
  const float* qb = (const float*)d_in[2];
  const float* kw = (const float*)d_in[3];
  const float* kb = (const float*)d_in[4];
  const float* vw = (const float*)d_in[5];
  const float* vb = (const float*)d_in[6];
  const float* lw = (const float*)d_in[7];
  const float* lb = (const float*)d_in[8];
  const float* ow = (const float*)d_in[9];
  const float* ob = (const float*)d_in[10];
  // d_in[11] = level_masks: unused — lvl(i,j) = 31 - clz((i+1)^j).

  char* ws = (char*)d_ws;
  size_t off = 0;
  auto alloc = [&](size_t bytes) -> char* {
    char* p = ws + off;
    off += (bytes + 255) & ~(size_t)255;
    return p;
  };
  bf16* xb     = (bf16*)alloc((size_t)M_ROWS * DM_SZ * 2);
  bf16* wqkvT  = (bf16*)alloc((size_t)N_PAD * DM_SZ * 2);  // rows 3264..3327 garbage (harmless)
  bf16* owT    = (bf16*)alloc((size_t)DM_SZ * DM_SZ * 2);
  bf16* Qp     = (bf16*)alloc((size_t)M_ROWS * DM_SZ * 2);
  bf16* Kpb    = (bf16*)alloc((size_t)M_ROWS * DM_SZ * 2);
  bf16* VTg    = (bf16*)alloc((size_t)M_ROWS * DM_SZ * 2);
  bf16* attn   = (bf16*)alloc((size_t)M_ROWS * DM_SZ * 2);
  float* logit = (float*)alloc((size_t)M_ROWS * H_SZ * L_SZ * 4);
  float* Hbuf  = (float*)alloc((size_t)32 * 16 * 4096 * 4);   // 8 MB leaf G's
  float* ksumb = (float*)alloc((size_t)32 * 16 * 64 * 4);     // 128 KB

  const dim3 blk(256);
  k_prep<<<dim3(16, 16, 6), blk, 0, stream>>>(x, xb, qw, kw, vw, ow, lw, wqkvT, owT);
  k_gemm_qkvl<<<dim3(N_PAD / 128, M_ROWS / 128), dim3(512), 0, stream>>>(
      xb, wqkvT, qb, kb, vb, lb, Qp, Kpb, VTg, logit);
  k_build<<<dim3(32 * 16), blk, 0, stream>>>(Kpb, VTg, Hbuf, ksumb);
  k_attn<<<dim3((T_SZ / 64) * B_SZ * H_SZ), blk, 0, stream>>>(
      Qp, Kpb, VTg, logit, Hbuf, ksumb, attn);
  k_gemm_out<<<dim3(DM_SZ / 64, M_ROWS / 64), blk, 0, stream>>>(attn, owT, ob, (float*)d_out);
}

// Round 4
// 171.214 us; speedup vs baseline: 1.0616x; 1.0616x over previous
//
#include <hip/hip_runtime.h>
#include <math.h>

typedef __bf16 bf16;
typedef __attribute__((ext_vector_type(4))) __bf16 bf16x4;
typedef __attribute__((ext_vector_type(8))) __bf16 bf16x8;
typedef __attribute__((ext_vector_type(4))) float f32x4;

#define B_SZ 2
#define T_SZ 1024
#define DM_SZ 1024
#define H_SZ 16
#define D_SZ 64
#define L_SZ 12
#define M_ROWS 2048      // B*T
#define N_PAD 3328       // q(1024)+k(1024)+v(1024)+logit(192)+pad(64)

__device__ __forceinline__ f32x4 mfma_16x16x32(bf16x8 a, bf16x8 b, f32x4 c) {
  return __builtin_amdgcn_mfma_f32_16x16x32_bf16(a, b, c, 0, 0, 0);
}

// async global->LDS, 16B/lane; LDS dest = wave-uniform base + lane*16.
__device__ __forceinline__ void gload_lds16(const bf16* g, bf16* l) {
  __builtin_amdgcn_global_load_lds((const __attribute__((address_space(1))) void*)g,
                                   (__attribute__((address_space(3))) void*)l,
                                   16, 0, 0);
}

// ---------------------------------------------------------------------------
// Prep: z=0..3 weight transposes (1024x1024), z=4 lw transpose (1024x192),
// z=5 x fp32->bf16 cast. Grid (16,16,6), block 256.
// ---------------------------------------------------------------------------
__global__ __launch_bounds__(256) void k_prep(
    const float* __restrict__ x, bf16* __restrict__ xb,
    const float* __restrict__ qw, const float* __restrict__ kw,
    const float* __restrict__ vw, const float* __restrict__ ow,
    const float* __restrict__ lw,
    bf16* __restrict__ wqkvT, bf16* __restrict__ owT) {
  const int z = blockIdx.z;
  const int t = threadIdx.x;
  if (z == 5) {  // cast 2048x1024 fp32 -> bf16, 8192 els per block
    const size_t base = ((size_t)blockIdx.y * 16 + blockIdx.x) * 8192 + t * 32;
#pragma unroll
    for (int u = 0; u < 4; ++u) {
      const float* p = x + base + u * 8;
      f32x4 a = *(const f32x4*)p;
      f32x4 b = *(const f32x4*)(p + 4);
      bf16x8 o;
#pragma unroll
      for (int e = 0; e < 4; ++e) { o[e] = (bf16)a[e]; o[e + 4] = (bf16)b[e]; }
      *(bf16x8*)(xb + base + u * 8) = o;
    }
    return;
  }
  __shared__ __align__(16) bf16 tile[64][66];
  const float* in; bf16* out; int C = 1024;
  if (z == 0)      { in = qw; out = wqkvT; }
  else if (z == 1) { in = kw; out = wqkvT + (size_t)1024 * DM_SZ; }
  else if (z == 2) { in = vw; out = wqkvT + (size_t)2048 * DM_SZ; }
  else if (z == 3) { in = ow; out = owT; }
  else             { in = lw; out = wqkvT + (size_t)3072 * DM_SZ; C = 192;
                     if (blockIdx.x >= 3) return; }
  const int tc = blockIdx.x * 64;
  const int tr = blockIdx.y * 64;
  const int r = t >> 2;
  const int c4 = (t & 3) << 4;
  const float* src = in + (size_t)(tr + r) * C + tc + c4;
  f32x4 f0 = *(const f32x4*)(src);
  f32x4 f1 = *(const f32x4*)(src + 4);
  f32x4 f2 = *(const f32x4*)(src + 8);
  f32x4 f3 = *(const f32x4*)(src + 12);
#pragma unroll
  for (int e = 0; e < 4; ++e) {
    tile[r][c4 + e]      = (bf16)f0[e];
    tile[r][c4 + 4 + e]  = (bf16)f1[e];
    tile[r][c4 + 8 + e]  = (bf16)f2[e];
    tile[r][c4 + 12 + e] = (bf16)f3[e];
  }
  __syncthreads();
  bf16x8 w0, w1;
#pragma unroll
  for (int e = 0; e < 8; ++e) { w0[e] = tile[c4 + e][r]; w1[e] = tile[c4 + 8 + e][r]; }
  bf16* dst = out + (size_t)(tc + r) * DM_SZ + tr + c4;
  *(bf16x8*)(dst) = w0;
  *(bf16x8*)(dst + 8) = w1;
}

// ---------------------------------------------------------------------------
// Fused QKVL GEMM: xb(2048x1024) x wqkvT(3328x1024) -> Qp/Kp (phi, bf16),
// VTg (plain, transposed in epilogue), logit (f32, raw). Tile 128x128.
// T4 pipeline: BK=32 steps, 3 LDS buffers (48KB), counted s_waitcnt vmcnt(4)
// + raw s_barrier per step — prefetch loads stay in flight ACROSS barriers
// (never drained to 0 in the main loop). Step s computes buf[s%3], stages
// step s+2 into buf[(s+2)%3] (= buffer read at step s-1, safe post-barrier).
// ---------------------------------------------------------------------------
__global__ __launch_bounds__(256) void k_gemm_qkvl(
    const bf16* __restrict__ A, const bf16* __restrict__ Wt,
    const float* __restrict__ qb, const float* __restrict__ kb,
    const float* __restrict__ vb, const float* __restrict__ lb,
    bf16* __restrict__ Qp, bf16* __restrict__ Kp,
    bf16* __restrict__ VTg, float* __restrict__ logit) {
  __shared__ __align__(16) char smem[49152];  // As3|Bs3 (48KB) / Trt (35KB)
  bf16* Asb = (bf16*)smem;           // [3][4096]  (128 rows x 32 cols)
  bf16* Bsb = Asb + 12288;           // [3][4096]
  const int nb = blockIdx.x * 128;
  const int mb = blockIdx.y * 128;
  const int t = threadIdx.x;
  const int wv = t >> 6;
  const int lane = t & 63;
  const int l16 = lane & 15;
  const int quad = lane >> 4;
  const int wm = (wv & 1) * 64;
  const int wn = (wv >> 1) * 64;

  const int trow = t >> 2;        // 0..63
  const int tcol = (t & 3) * 8;

  const f32x4 zero4 = {0.f, 0.f, 0.f, 0.f};
  f32x4 acc[4][4];
#pragma unroll
  for (int i = 0; i < 4; ++i)
#pragma unroll
    for (int j = 0; j < 4; ++j) acc[i][j] = zero4;

  const bf16* ag = A + (size_t)(mb + trow) * DM_SZ + tcol;
  const bf16* bg = Wt + (size_t)(nb + trow) * DM_SZ + tcol;

  // stage one BK=32 step (4 gload_lds per wave)
  auto stage = [&](int k0, int buf) {
    bf16* As = Asb + buf * 4096;
    bf16* Bs = Bsb + buf * 4096;
    gload_lds16(ag + k0, As + t * 8);
    gload_lds16(ag + (size_t)64 * DM_SZ + k0, As + 2048 + t * 8);
    gload_lds16(bg + k0, Bs + t * 8);
    gload_lds16(bg + (size_t)64 * DM_SZ + k0, Bs + 2048 + t * 8);
  };

  auto computeStep = [&](int buf) {
    const bf16* As = Asb + buf * 4096;
    const bf16* Bs = Bsb + buf * 4096;
    bf16x8 af[4];
#pragma unroll
    for (int mi = 0; mi < 4; ++mi)
      af[mi] = *(const bf16x8*)(As + (wm + mi * 16 + l16) * 32 + quad * 8);
#pragma unroll
    for (int ni = 0; ni < 4; ++ni) {
      bf16x8 bfr = *(const bf16x8*)(Bs + (wn + ni * 16 + l16) * 32 + quad * 8);
#pragma unroll
      for (int mi = 0; mi < 4; ++mi)
        acc[mi][ni] = mfma_16x16x32(af[mi], bfr, acc[mi][ni]);
    }
  };

  stage(0, 0);
  stage(32, 1);
  int cb = 0, sb = 2;
  for (int k0 = 0; k0 < DM_SZ - 32; k0 += 32) {  // steps 0..30
    asm volatile("s_waitcnt vmcnt(4)" ::: "memory");  // retire this step's 4
    __builtin_amdgcn_s_barrier();
    __builtin_amdgcn_sched_barrier(0);
    if (k0 + 64 < DM_SZ) stage(k0 + 64, sb);
    computeStep(cb);
    cb = (cb == 2) ? 0 : cb + 1;
    sb = (sb == 2) ? 0 : sb + 1;
  }
  // final step (31): only its own 4 loads outstanding -> full drain
  asm volatile("s_waitcnt vmcnt(0)" ::: "memory");
  __builtin_amdgcn_s_barrier();
  __builtin_amdgcn_sched_barrier(0);
  computeStep(cb);

  const int seg = nb >> 10;  // 0=q 1=k 2=v 3=logit
  if (seg < 2) {
    const float* bias = seg == 0 ? qb : kb;
    bf16* outp = seg == 0 ? Qp : Kp;
    const int c0 = (nb & 1023) + wn;
#pragma unroll
    for (int ni = 0; ni < 4; ++ni) {
      const int col = c0 + ni * 16 + l16;
      const float bv = bias[col];
#pragma unroll
      for (int mi = 0; mi < 4; ++mi) {
#pragma unroll
        for (int r = 0; r < 4; ++r) {
          const int row = mb + wm + mi * 16 + quad * 4 + r;
          float v = acc[mi][ni][r] + bv;
          v = (v > 0.f) ? (v + 1.f) : __expf(v);
          outp[(size_t)row * DM_SZ + col] = (bf16)v;
        }
      }
    }
  } else if (seg == 2) {
    // V: bias, transpose via LDS (stride 136), store VTg[b*1024+d][t]
    bf16* Trt = (bf16*)smem;
    const int cb2 = nb - 2048;
    __syncthreads();  // K-loop LDS frag reads complete before overwrite
#pragma unroll
    for (int ni = 0; ni < 4; ++ni) {
      const int nloc = wn + ni * 16 + l16;
      const float bv = vb[cb2 + nloc];
#pragma unroll
      for (int mi = 0; mi < 4; ++mi) {
        const int mloc = wm + mi * 16 + quad * 4;
        bf16x4 pk;
#pragma unroll
        for (int r = 0; r < 4; ++r) pk[r] = (bf16)(acc[mi][ni][r] + bv);
        *(bf16x4*)&Trt[nloc * 136 + mloc] = pk;
      }
    }
    __syncthreads();
    const int dn = t >> 1, ch = t & 1;
    const int bq = mb >> 10;
    const int m0g = mb & 1023;
    bf16* dst = VTg + ((size_t)(bq * 1024 + cb2 + dn)) * T_SZ + m0g + ch * 64;
    const bf16* srcl = Trt + dn * 136 + ch * 64;
#pragma unroll
    for (int e = 0; e < 8; ++e)
      *(bf16x8*)(dst + e * 8) = *(const bf16x8*)(srcl + e * 8);
  } else {
    const int lc0 = (nb - 3072) + wn;
#pragma unroll
    for (int ni = 0; ni < 4; ++ni) {
      const int lcol = lc0 + ni * 16 + l16;
      if (lcol < H_SZ * L_SZ) {
        const float bv = lb[lcol];
#pragma unroll
        for (int mi = 0; mi < 4; ++mi) {
#pragma unroll
          for (int r = 0; r < 4; ++r) {
            const int row = mb + wm + mi * 16 + quad * 4 + r;
            logit[(size_t)row * (H_SZ * L_SZ) + lcol] = acc[mi][ni][r] + bv;
          }
        }
      }
    }
  }
}

// ---------------------------------------------------------------------------
// Leaf build: per (bh, jt) compute G[d2][d1] = sum_j V[j][d2]*Kp[j][d1]
// (64x64, f32) and ksum[d1] = sum_j Kp[j][d1]. Grid 512, block 256.
// ---------------------------------------------------------------------------
__global__ __launch_bounds__(256) void k_build(const bf16* __restrict__ Kp,
                                               const bf16* __restrict__ VTg,
                                               float* __restrict__ Hbuf,
                                               float* __restrict__ ksumbuf) {
  __shared__ __align__(16) bf16 KTs[64][72];  // [d1][j]
  __shared__ __align__(16) bf16 VTs[64][72];  // [d2][j]
  const int idx = blockIdx.x;
  const int bh = idx & 31;
  const int jt = idx >> 5;
  const int b = bh >> 4, h = bh & 15;
  const int t = threadIdx.x;
  const int wv = t >> 6, lane = t & 63, l16 = lane & 15, quad = lane >> 4;
  const int r = t >> 2, c = (t & 3) << 4;

  // stage V^T rows directly (VTg is [d][t])
  const bf16* vp = VTg + ((size_t)bh * 64 + r) * T_SZ + jt * 64 + c;
  bf16x8 v0 = *(const bf16x8*)vp;
  bf16x8 v1 = *(const bf16x8*)(vp + 8);
  // Kp rows [j][d] -> transpose into KTs[d][j]
  const bf16* kp = Kp + ((size_t)b * T_SZ + jt * 64 + r) * DM_SZ + h * 64 + c;
  bf16x8 k0 = *(const bf16x8*)kp;
  bf16x8 k1 = *(const bf16x8*)(kp + 8);
  *(bf16x8*)&VTs[r][c] = v0;
  *(bf16x8*)&VTs[r][c + 8] = v1;
#pragma unroll
  for (int e = 0; e < 8; ++e) { KTs[c + e][r] = k0[e]; KTs[c + 8 + e][r] = k1[e]; }
  __syncthreads();

  if (t < 64) {
    float s = 0.f;
#pragma unroll
    for (int j = 0; j < 64; ++j) s += (float)KTs[t][j];
    ksumbuf[((size_t)bh * 16 + jt) * 64 + t] = s;
  }

  const f32x4 zero4 = {0.f, 0.f, 0.f, 0.f};
  f32x4 acc[4];
#pragma unroll
  for (int tn = 0; tn < 4; ++tn) acc[tn] = zero4;
#pragma unroll
  for (int ks = 0; ks < 2; ++ks) {
    bf16x8 af = *(const bf16x8*)&VTs[wv * 16 + l16][ks * 32 + quad * 8];
#pragma unroll
    for (int tn = 0; tn < 4; ++tn) {
      bf16x8 bfr = *(const bf16x8*)&KTs[tn * 16 + l16][ks * 32 + quad * 8];
      acc[tn] = mfma_16x16x32(af, bfr, acc[tn]);
    }
  }
  float* hp = Hbuf + ((size_t)bh * 16 + jt) * 4096;
#pragma unroll
  for (int tn = 0; tn < 4; ++tn)
#pragma unroll
    for (int rr = 0; rr < 4; ++rr)
      hp[(wv * 16 + quad * 4 + rr) * 64 + tn * 16 + l16] = acc[tn][rr];
}

// ---------------------------------------------------------------------------
// Fenwick-associated attention (see round-2 notes). Grid 512, block 256.
// ---------------------------------------------------------------------------
__global__ __launch_bounds__(256) void k_attn(const bf16* __restrict__ Qp,
                                              const bf16* __restrict__ Kp,
                                              const bf16* __restrict__ VTg,
                                              const float* __restrict__ Lg,
                                              const float* __restrict__ Hbuf,
                                              const float* __restrict__ ksumbuf,
                                              bf16* __restrict__ O) {
  __shared__ __align__(16) bf16 Ks[64][72];
  __shared__ __align__(16) bf16 VTs[64][72];
  __shared__ __align__(16) bf16 Ms[4][64][72];
  __shared__ __align__(16) bf16 Pl[4][16][80];
  __shared__ __align__(16) bf16 Bdvs[16][72];
  __shared__ float Ws[64 * L_SZ];
  __shared__ float q63s[64];
  __shared__ float y63s[64];
  __shared__ float dsum63s;

  const int idx = blockIdx.x;
  const int s = idx >> 5;
  const int bh = idx & 31;
  const int it = (s < 8) ? (15 - s) : (s - 8);  // heavy-first balance
  const int b = bh >> 4;
  const int h = bh & 15;
  const int i0 = it * 64;
  const int t = threadIdx.x;
  const int wv = t >> 6;
  const int lane = t & 63;
  const int l16 = lane & 15;
  const int quad = lane >> 4;
  const int m0 = wv * 16;
  const size_t base_bt = (size_t)b * T_SZ;

  // init
  for (int i = t; i < 16 * 72; i += 256) ((short*)Bdvs)[i] = 0;
  if (t < 64) y63s[t] = 0.f;
  if (t == 0) dsum63s = 0.f;

  // Q fragments (A operand, k = d)
  const bf16* qptr = Qp + (base_bt + i0 + m0 + l16) * DM_SZ + h * 64 + quad * 8;
  const bf16x8 aq0 = *(const bf16x8*)(qptr);
  const bf16x8 aq1 = *(const bf16x8*)(qptr + 32);

  // q63 staging
  if (t < 64) q63s[t] = (float)Qp[(base_bt + i0 + 63) * DM_SZ + h * 64 + t];

  // diag K/V tile loads to regs (written to LDS after sync1)
  const int sr = t >> 2;
  const int sc = (t & 3) << 4;
  const bf16* kpg = Kp + (base_bt + i0 + sr) * DM_SZ + h * 64 + sc;
  const bf16x8 kv0 = *(const bf16x8*)(kpg);
  const bf16x8 kv1 = *(const bf16x8*)(kpg + 8);
  const bf16* vpg = VTg + ((size_t)bh * 64 + sr) * T_SZ + i0 + sc;
  const bf16x8 vv0 = *(const bf16x8*)(vpg);
  const bf16x8 vv1 = *(const bf16x8*)(vpg + 8);

  if (t < 64) {  // fused softmax for this block's 64 query rows
    const float* lp = Lg + (base_bt + i0 + t) * (H_SZ * L_SZ) + h * L_SZ;
    float v[L_SZ];
    float m = -1e30f;
#pragma unroll
    for (int l = 0; l < L_SZ; ++l) { v[l] = lp[l]; m = fmaxf(m, v[l]); }
    float sum = 0.f;
#pragma unroll
    for (int l = 0; l < L_SZ; ++l) { v[l] = __expf(v[l] - m); sum += v[l]; }
    const float inv = 1.f / sum;
#pragma unroll
    for (int l = 0; l < L_SZ; ++l) Ws[t * L_SZ + l] = v[l] * inv;
  }

  __syncthreads();  // Ws, q63s, zero-inits visible

  // write diag tiles (padded 72: read stride 144B -> 2-way = free)
  *(bf16x8*)&Ks[sr][sc] = kv0;
  *(bf16x8*)&Ks[sr][sc + 8] = kv1;
  *(bf16x8*)&VTs[sr][sc] = vv0;
  *(bf16x8*)&VTs[sr][sc + 8] = vv1;

  const int il_base = m0 + quad * 4;
  const f32x4 zero4 = {0.f, 0.f, 0.f, 0.f};
  f32x4 accn[4];
#pragma unroll
  for (int tn = 0; tn < 4; ++tn) accn[tn] = zero4;
  float den[4] = {0.f, 0.f, 0.f, 0.f};

  // ---- phase 2: group-sum leaves + row-63 weighted stream ----
  if (it > 0) {
    const float* hb = Hbuf + (size_t)bh * 16 * 4096;
    const float* ksb = ksumbuf + (size_t)bh * 16 * 64;
    f32x4 m63a[4];
#pragma unroll
    for (int i = 0; i < 4; ++i) m63a[i] = zero4;
    float dv63 = 0.f;
    int x = it;
    while (x > 0) {
      const int g = __builtin_ctz((unsigned)x);
      const int lo = x - (1 << g);
      f32x4 ma[4];
#pragma unroll
      for (int i = 0; i < 4; ++i) ma[i] = zero4;
      float dva = 0.f;
      for (int jt = lo; jt < x; ++jt) {
        const float wB = Ws[63 * L_SZ + 6 + (31 - __clz((unsigned)((it + 1) ^ jt)))];
        const float* lp = hb + jt * 4096 + t * 16;
#pragma unroll
        for (int i = 0; i < 4; ++i) {
          f32x4 hv = *(const f32x4*)(lp + i * 4);
#pragma unroll
          for (int e = 0; e < 4; ++e) {
            ma[i][e] += hv[e];
            m63a[i][e] += wB * hv[e];
          }
        }
        if (t < 64) {
          const float ksv = ksb[jt * 64 + t];
          dva += ksv;
          dv63 += wB * ksv;
        }
      }
      // flush group g: Ms[g][d2][d1]
      bf16x8 o0, o1;
#pragma unroll
      for (int e = 0; e < 4; ++e) {
        o0[e] = (bf16)ma[0][e]; o0[e + 4] = (bf16)ma[1][e];
        o1[e] = (bf16)ma[2][e]; o1[e + 4] = (bf16)ma[3][e];
      }
      *(bf16x8*)&Ms[g][t >> 2][(t & 3) << 4] = o0;
      *(bf16x8*)&Ms[g][t >> 2][((t & 3) << 4) + 8] = o1;
      if (t < 64) Bdvs[g][t] = (bf16)dva;
      x = lo;
    }
    // y63[d2] = sum_d1 q63[d1] * Mw63[d2][d1]
    float p63 = 0.f;
    const int d1b = (t & 3) << 4;
#pragma unroll
    for (int i = 0; i < 4; ++i)
#pragma unroll
      for (int e = 0; e < 4; ++e) p63 += q63s[d1b + i * 4 + e] * m63a[i][e];
    p63 += __shfl_xor(p63, 1, 64);
    p63 += __shfl_xor(p63, 2, 64);
    if ((t & 3) == 0) y63s[t >> 2] = p63;
    if (t < 64) {
      float pd = q63s[t] * dv63;
      pd += __shfl_xor(pd, 1, 64);
      pd += __shfl_xor(pd, 2, 64);
      pd += __shfl_xor(pd, 4, 64);
      pd += __shfl_xor(pd, 8, 64);
      pd += __shfl_xor(pd, 16, 64);
      pd += __shfl_xor(pd, 32, 64);
      if (t == 0) dsum63s = pd;
    }
  }
  __syncthreads();  // Ms, Bdvs, Ks, VTs, y63s, dsum63s visible

  // ---- phase 3: group GEMMs + dv MFMA ----
  if (it > 0) {
    int x = it;
    while (x > 0) {
      const int g = __builtin_ctz((unsigned)x);
      f32x4 ya[4];
#pragma unroll
      for (int tn = 0; tn < 4; ++tn) ya[tn] = zero4;
#pragma unroll
      for (int ks = 0; ks < 2; ++ks) {
        const bf16x8 af = ks ? aq1 : aq0;
#pragma unroll
        for (int tn = 0; tn < 4; ++tn) {
          bf16x8 bfr = *(const bf16x8*)&Ms[g][tn * 16 + l16][ks * 32 + quad * 8];
          ya[tn] = mfma_16x16x32(af, bfr, ya[tn]);
        }
      }
      float wg[4];
#pragma unroll
      for (int r = 0; r < 4; ++r) {
        const int il = il_base + r;
        wg[r] = (il == 63) ? 0.f : Ws[il * L_SZ + 6 + g];
      }
#pragma unroll
      for (int tn = 0; tn < 4; ++tn)
#pragma unroll
        for (int r = 0; r < 4; ++r) accn[tn][r] += wg[r] * ya[tn][r];
      x -= 1 << g;
    }
    f32x4 da = zero4;
#pragma unroll
    for (int ks = 0; ks < 2; ++ks) {
      const bf16x8 af = ks ? aq1 : aq0;
      bf16x8 bfr = *(const bf16x8*)&Bdvs[l16][ks * 32 + quad * 8];
      da = mfma_16x16x32(af, bfr, da);
    }
#pragma unroll
    for (int r = 0; r < 4; ++r) {
      const int il = il_base + r;
      const float wd = (il == 63) ? 0.f : Ws[il * L_SZ + 6 + (l16 & 3)];
      den[r] += wd * da[r];
    }
  }

  // ---- phase 4: diagonal tile (exact levels + causal mask) ----
  {
    f32x4 sacc[4];
    __builtin_amdgcn_s_setprio(1);
#pragma unroll
    for (int tn = 0; tn < 4; ++tn) {
      sacc[tn] = zero4;
      bf16x8 bk0 = *(const bf16x8*)&Ks[tn * 16 + l16][quad * 8];
      bf16x8 bk1 = *(const bf16x8*)&Ks[tn * 16 + l16][32 + quad * 8];
      sacc[tn] = mfma_16x16x32(aq0, bk0, sacc[tn]);
      sacc[tn] = mfma_16x16x32(aq1, bk1, sacc[tn]);
    }
    __builtin_amdgcn_s_setprio(0);
#pragma unroll
    for (int tn = 0; tn < 4; ++tn) {
#pragma unroll
      for (int r = 0; r < 4; ++r) {
        const int il = il_base + r;
        const int ig = i0 + il;
        const int jg = i0 + tn * 16 + l16;
        float p = 0.f;
        if (jg <= ig) {
          const int lvl = 31 - __clz((unsigned)((ig + 1) ^ jg));
          p = sacc[tn][r] * Ws[il * L_SZ + lvl];
        }
        den[r] += p;
        Pl[wv][quad * 4 + r][(tn * 16 + l16) ^ (quad << 4)] = (bf16)p;
      }
    }
    __builtin_amdgcn_s_setprio(1);
#pragma unroll
    for (int ks = 0; ks < 2; ++ks) {
      bf16x8 apf = *(const bf16x8*)&Pl[wv][l16][(ks * 32 + quad * 8) ^ ((l16 >> 2) << 4)];
#pragma unroll
      for (int tn = 0; tn < 4; ++tn) {
        bf16x8 bvf = *(const bf16x8*)&VTs[tn * 16 + l16][ks * 32 + quad * 8];
        accn[tn] = mfma_16x16x32(apf, bvf, accn[tn]);
      }
    }
    __builtin_amdgcn_s_setprio(0);
  }

  // ---- reduce + output ----
#pragma unroll
  for (int r = 0; r < 4; ++r) {
    float d = den[r];
    d += __shfl_xor(d, 1, 64);
    d += __shfl_xor(d, 2, 64);
    d += __shfl_xor(d, 4, 64);
    d += __shfl_xor(d, 8, 64);
    den[r] = d;
  }
  if (il_base + 3 == 63) den[3] += dsum63s;  // row-63 off-diag denominator
#pragma unroll
  for (int r = 0; r < 4; ++r) den[r] = fmaxf(den[r], 1e-6f);

#pragma unroll
  for (int tn = 0; tn < 4; ++tn) {
#pragma unroll
    for (int r = 0; r < 4; ++r) {
      const int il = il_base + r;
      float v = accn[tn][r];
      if (il == 63) v += y63s[tn * 16 + l16];
      O[(base_bt + i0 + il) * DM_SZ + h * 64 + tn * 16 + l16] =
          (bf16)(v / den[r]);
    }
  }
}

// ---------------------------------------------------------------------------
// Output GEMM: attn(2048x1024) x owT(1024x1024) + ob -> f32 out.
// Tile 64x64, grid (16,32)=512 blocks. Same T4 counted-vmcnt/raw-barrier
// pipeline as k_gemm_qkvl: BK=32, 3 buffers (24KB), vmcnt(2) per step.
// ---------------------------------------------------------------------------
__global__ __launch_bounds__(256) void k_gemm_out(const bf16* __restrict__ A,
                                                  const bf16* __restrict__ Wt,
                                                  const float* __restrict__ ob,
                                                  float* __restrict__ out) {
  __shared__ __align__(16) bf16 As[3][2048];  // 64 rows x 32 cols
  __shared__ __align__(16) bf16 Bs[3][2048];
  const int nb = blockIdx.x * 64;
  const int mb = blockIdx.y * 64;
  const int t = threadIdx.x;
  const int wv = t >> 6;
  const int lane = t & 63;
  const int l16 = lane & 15;
  const int quad = lane >> 4;
  const int wm = wv * 16;

  const int trow = t >> 2;        // 0..63
  const int tcol = (t & 3) * 8;

  const f32x4 zero4 = {0.f, 0.f, 0.f, 0.f};
  f32x4 acc[4];
#pragma unroll
  for (int j = 0; j < 4; ++j) acc[j] = zero4;

  const bf16* ag = A + (size_t)(mb + trow) * DM_SZ + tcol;
  const bf16* bg = Wt + (size_t)(nb + trow) * DM_SZ + tcol;

  auto stageg = [&](int k0, int buf) {
    gload_lds16(ag + k0, As[buf] + t * 8);
    gload_lds16(bg + k0, Bs[buf] + t * 8);
  };
  auto computeStep = [&](int buf) {
    bf16x8 af = *(const bf16x8*)(As[buf] + (wm + l16) * 32 + quad * 8);
#pragma unroll
    for (int ni = 0; ni < 4; ++ni) {
      bf16x8 bfr = *(const bf16x8*)(Bs[buf] + (ni * 16 + l16) * 32 + quad * 8);
      acc[ni] = mfma_16x16x32(af, bfr, acc[ni]);
    }
  };

  stageg(0, 0);
  stageg(32, 1);
  int cb = 0, sb = 2;
  for (int k0 = 0; k0 < DM_SZ - 32; k0 += 32) {  // steps 0..30
    asm volatile("s_waitcnt vmcnt(2)" ::: "memory");
    __builtin_amdgcn_s_barrier();
    __builtin_amdgcn_sched_barrier(0);
    if (k0 + 64 < DM_SZ) stageg(k0 + 64, sb);
    computeStep(cb);
    cb = (cb == 2) ? 0 : cb + 1;
    sb = (sb == 2) ? 0 : sb + 1;
  }
  asm volatile("s_waitcnt vmcnt(0)" ::: "memory");
  __builtin_amdgcn_s_barrier();
  __builtin_amdgcn_sched_barrier(0);
  computeStep(cb);

#pragma unroll
  for (int ni = 0; ni < 4; ++ni) {
    const int col = nb + ni * 16 + l16;
    const float bv = ob[col];
#pragma unroll
    for (int r = 0; r < 4; ++r) {
      const int row = mb + wm + quad * 4 + r;
      out[(size_t)row * DM_SZ + col] = acc[ni][r] + bv;
    }
  }
}

// ---------------------------------------------------------------------------
extern "C" void kernel_launch(void* const* d_in, const int* in_sizes, int n_in,
                              void* d_out, int out_size, void* d_ws, size_t ws_size,
                              hipStream_t stream) {
  (void)in_sizes; (void)n_in; (void)out_size; (void)ws_size;
  const float* x  = (const float*)d_in[0];
  const float* qw = (const float*)d_in[1];
  const float* qb = (const float*)d_in[2];
  const float* kw = (const float*)d_in[3];
  const float* kb = (const float*)d_in[4];
  const float* vw = (const float*)d_in[5];
  const float* vb = (const float*)d_in[6];
  const float* lw = (const float*)d_in[7];
  const float* lb = (const float*)d_in[8];
  const float* ow = (const float*)d_in[9];
  const float* ob = (const float*)d_in[10];
  // d_in[11] = level_masks: unused — lvl(i,j) = 31 - clz((i+1)^j).

  char* ws = (char*)d_ws;
  size_t off = 0;
  auto alloc = [&](size_t bytes) -> char* {
    char* p = ws + off;
    off += (bytes + 255) & ~(size_t)255;
    return p;
  };
  bf16* xb     = (bf16*)alloc((size_t)M_ROWS * DM_SZ * 2);
  bf16* wqkvT  = (bf16*)alloc((size_t)N_PAD * DM_SZ * 2);  // rows 3264..3327 garbage (harmless)
  bf16* owT    = (bf16*)alloc((size_t)DM_SZ * DM_SZ * 2);
  bf16* Qp     = (bf16*)alloc((size_t)M_ROWS * DM_SZ * 2);
  bf16* Kpb    = (bf16*)alloc((size_t)M_ROWS * DM_SZ * 2);
  bf16* VTg    = (bf16*)alloc((size_t)M_ROWS * DM_SZ * 2);
  bf16* attn   = (bf16*)alloc((size_t)M_ROWS * DM_SZ * 2);
  float* logit = (float*)alloc((size_t)M_ROWS * H_SZ * L_SZ * 4);
  float* Hbuf  = (float*)alloc((size_t)32 * 16 * 4096 * 4);   // 8 MB leaf G's
  float* ksumb = (float*)alloc((size_t)32 * 16 * 64 * 4);     // 128 KB

  const dim3 blk(256);
  k_prep<<<dim3(16, 16, 6), blk, 0, stream>>>(x, xb, qw, kw, vw, ow, lw, wqkvT, owT);
  k_gemm_qkvl<<<dim3(N_PAD / 128, M_ROWS / 128), blk, 0, stream>>>(
      xb, wqkvT, qb, kb, vb, lb, Qp, Kpb, VTg, logit);
  k_build<<<dim3(32 * 16), blk, 0, stream>>>(Kpb, VTg, Hbuf, ksumb);
  k_attn<<<dim3((T_SZ / 64) * B_SZ * H_SZ), blk, 0, stream>>>(
      Qp, Kpb, VTg, logit, Hbuf, ksumb, attn);
  k_gemm_out<<<dim3(DM_SZ / 64, M_ROWS / 64), blk, 0, stream>>>(attn, owT, ob, (float*)d_out);
}